// Round 15
// baseline (4509.701 us; speedup 1.0000x reference)
//
#include <hip/hip_runtime.h>
#include <stdint.h>

// ---- problem constants ----
constexpr int HD   = 512;
constexpr int TS   = 256;
constexpr int NB   = 64;
constexpr int MBR  = 128;
constexpr int SLAB = MBR * HD;   // 65536 elements per h-slab

typedef __attribute__((ext_vector_type(8))) short bf16x8;
typedef __attribute__((ext_vector_type(4))) float f32x4;

__device__ __forceinline__ unsigned short f2bf(float f){
  union { float f; unsigned u; } v; v.f = f;
  unsigned r = v.u + 0x7fffu + ((v.u >> 16) & 1u);
  return (unsigned short)(r >> 16);
}
__device__ __forceinline__ float fsig(float x){ return 1.f / (1.f + __expf(-x)); }
__device__ __forceinline__ float ftanh(float x){ return 1.f - 2.f / (__expf(2.f * x) + 1.f); }
__device__ __forceinline__ bf16x8 pack8(float4 a, float4 b){
  bf16x8 w;
  w[0]=(short)f2bf(a.x); w[1]=(short)f2bf(a.y); w[2]=(short)f2bf(a.z); w[3]=(short)f2bf(a.w);
  w[4]=(short)f2bf(b.x); w[5]=(short)f2bf(b.y); w[6]=(short)f2bf(b.z); w[7]=(short)f2bf(b.w);
  return w;
}

// Wcf: weights pre-packed in MFMA B-fragment order.
// Layout [layer][slice(32)][cg(4)][kc(32)][lane(64)][e(8)] bf16:
//   lane: c16 = lane&15 -> col within 16-col frag, kg = lane>>4 -> k-group.
//   col  = gate*512 + unit, unit = slice*16 + cg*4 + (c16>>2), gate = c16&3.
//   k    = kc*32 + kg*8 + e   (k<512: W_ih, k>=512: W_hh).
// Per (slice,cg,kc): 64 lanes x 16 B = contiguous 1 KB = one coalesced wave load.
__global__ void prep_wcf(const float* __restrict__ Wih0, const float* __restrict__ Whh0,
                         const float* __restrict__ Wih1, const float* __restrict__ Whh1,
                         unsigned short* __restrict__ Wcf){
  int idx   = blockIdx.x * 256 + threadIdx.x;   // 0 .. 4M-1
  int e     = idx & 7;
  int lane  = (idx >> 3) & 63;
  int kc    = (idx >> 9) & 31;
  int cg    = (idx >> 14) & 3;
  int slice = (idx >> 16) & 31;
  int layer = idx >> 21;
  int c16 = lane & 15, kg = lane >> 4;
  int unit = slice * 16 + cg * 4 + (c16 >> 2);
  int gate = c16 & 3;
  int n = gate * HD + unit;
  int k = kc * 32 + kg * 8 + e;
  const float* Wih = layer ? Wih1 : Wih0;
  const float* Whh = layer ? Whh1 : Whh0;
  float v = (k < HD) ? Wih[(size_t)n * HD + k] : Whh[(size_t)n * HD + (k - HD)];
  Wcf[idx] = f2bf(v);
}

__global__ void prep_bias(const float* __restrict__ a, const float* __restrict__ b,
                          float* __restrict__ o){
  int i = blockIdx.x * 256 + threadIdx.x;
  if (i < 2048) o[i] = a[i] + b[i];
}

// One pipeline step as ONE graph node. L0 computes t=s; L1 computes t=s-2.
// Ordering and memory visibility come from kernel boundaries in the stream —
// no flags, no polls, no fences, no placement assumptions.
// 256 WGs x 512 thr: wg>>7 = layer, (wg>>5)&3 = grp (32 rows), wg&31 = slice
// (16 units). Wave wv: wgrp = wv&3 (16 gate-cols), mi = wv>>2 (16 rows).
// Weights read per step from Wcf (fragment-packed, coalesced, L2/L3-resident).
__global__ __launch_bounds__(512)
void lstm_step(const float* __restrict__ text,
               const unsigned short* __restrict__ Wcf,
               const float* __restrict__ bias,     // [2][2048]
               unsigned short* __restrict__ h0x,   // [256][128][512] write-once
               unsigned short* __restrict__ h1r,   // [4][128][512] ring
               float* __restrict__ Cst,            // [2][128][512] cell state
               float* __restrict__ H1f,            // [128][512] final h1 fp32
               int s)
{
  const int wg    = blockIdx.x;
  const int layer = wg >> 7;
  const int t     = layer ? (s - 2) : s;
  if (t < 0 || t >= TS) return;
  const int grp   = (wg >> 5) & 3;
  const int slice = wg & 31;
  const int m0    = grp * 32;
  const int u0    = slice * 16;
  const int tid   = threadIdx.x;
  const int wv    = tid >> 6;
  const int l     = tid & 63;
  const int lj    = l & 15;
  const int lk    = l >> 4;
  const int wgrp  = wv & 3;
  const int mi    = wv >> 2;

  const int myunit = u0 + wgrp * 4 + (lj >> 2);
  const int mygate = lj & 3;
  const float bgv  = bias[layer * 2048 + mygate * HD + myunit];
  const int arow   = m0 + mi * 16 + lj;
  const int aoff   = arow * HD + lk * 8;

  // B-fragment stream for this (layer, slice, wgrp): 32 x 1 KB contiguous blocks
  const unsigned short* wb =
      Wcf + ((size_t)(layer * 128 + slice * 4 + wgrp) * 32) * 512 + (size_t)l * 8;

  f32x4 acc = {0.f, 0.f, 0.f, 0.f};

  // ---- input half (kc 0..15): x_t @ W_ih (L0) or h0[t] @ W_ih1 (L1) ----
  if (layer == 0){
    int b   = arow & 63;
    int ts2 = (arow < 64) ? t : (TS - 1 - t);
    const float* src = text + ((size_t)b * TS + ts2) * HD + lk * 8;
    #pragma unroll
    for (int kc = 0; kc < 16; ++kc){
      const float* sp = src + kc * 32;
      bf16x8 a = pack8(((const float4*)sp)[0], ((const float4*)sp)[1]);
      bf16x8 bf = *(const bf16x8*)(wb + (size_t)kc * 512);
      acc = __builtin_amdgcn_mfma_f32_16x16x32_bf16(a, bf, acc, 0, 0, 0);
    }
  } else {
    const unsigned short* src = h0x + (size_t)t * SLAB + aoff;
    #pragma unroll
    for (int kc = 0; kc < 16; ++kc){
      bf16x8 a  = *(const bf16x8*)(src + kc * 32);
      bf16x8 bf = *(const bf16x8*)(wb + (size_t)kc * 512);
      acc = __builtin_amdgcn_mfma_f32_16x16x32_bf16(a, bf, acc, 0, 0, 0);
    }
  }
  // ---- recurrent half (kc 16..31): h[t-1] @ W_hh ----
  if (t > 0){
    const unsigned short* src = layer
        ? (h1r + (size_t)((t - 1) & 3) * SLAB + aoff)
        : (h0x + (size_t)(t - 1) * SLAB + aoff);
    #pragma unroll
    for (int kc = 0; kc < 16; ++kc){
      bf16x8 a  = *(const bf16x8*)(src + kc * 32);
      bf16x8 bf = *(const bf16x8*)(wb + (size_t)(16 + kc) * 512);
      acc = __builtin_amdgcn_mfma_f32_16x16x32_bf16(a, bf, acc, 0, 0, 0);
    }
  }

  // ---- cell update (C/D: col = lane&15 -> unit/gate; row = lk*4 + r) ----
  float* cbase = Cst + (size_t)layer * SLAB;
  unsigned short* hout = layer ? (h1r + (size_t)(t & 3) * SLAB)
                               : (h0x + (size_t)t * SLAB);
  const bool wrF = (layer == 1) && (t == TS - 1);
  #pragma unroll
  for (int r = 0; r < 4; ++r){
    float v  = acc[r] + bgv;
    float v1 = __shfl_xor(v, 1);
    float v2 = __shfl_xor(v, 2);
    float v3 = __shfl_xor(v, 3);
    auto pick = [&](int m)->float {
      return m == 0 ? v : (m == 1 ? v1 : (m == 2 ? v2 : v3));
    };
    float gi = pick(mygate);
    float gf = pick(mygate ^ 1);
    float gg = pick(mygate ^ 2);
    float go = pick(mygate ^ 3);
    float i_ = fsig(gi);
    float f_ = fsig(gf);
    float g_ = ftanh(gg);
    float o_ = fsig(go);
    int row   = m0 + mi * 16 + lk * 4 + r;
    size_t ci = (size_t)row * HD + myunit;
    float c   = f_ * cbase[ci] + i_ * g_;
    if (mygate == 0) cbase[ci] = c;
    float h   = o_ * ftanh(c);
    int hb    = (int)f2bf(h);
    int pb    = __shfl_xor(hb, 4);           // partner unit (myunit+1)
    if ((lj & 7) == 0)                       // lj in {0,8}: even units, gate 0
      *(unsigned*)((char*)hout + ((size_t)row * HD + myunit) * 2)
          = (unsigned)((hb & 0xffff) | (pb << 16));
    if (wrF && mygate == 0)
      H1f[(size_t)row * HD + myunit] = h;
  }
}

// out[b] = dot(h1_fwd[b], Wlin[0:512]) + dot(h1_rev[b], Wlin[512:1024]) + blin
__global__ void final_linear(const float* __restrict__ H1f, const float* __restrict__ Wlin,
                             const float* __restrict__ blin, float* __restrict__ out){
  int b = blockIdx.x, l = threadIdx.x;
  float s = 0.f;
  for (int j = l; j < HD; j += 64) s += H1f[(size_t)b * HD + j]        * Wlin[j];
  for (int j = l; j < HD; j += 64) s += H1f[(size_t)(NB + b) * HD + j] * Wlin[HD + j];
  #pragma unroll
  for (int off = 32; off; off >>= 1) s += __shfl_down(s, off);
  if (l == 0) out[b] = s + blin[0];
}

extern "C" void kernel_launch(void* const* d_in, const int* in_sizes, int n_in,
                              void* d_out, int out_size, void* d_ws, size_t ws_size,
                              hipStream_t stream)
{
  const float* text = (const float*)d_in[0];
  const float* Wih0 = (const float*)d_in[1];
  const float* Whh0 = (const float*)d_in[2];
  const float* bih0 = (const float*)d_in[3];
  const float* bhh0 = (const float*)d_in[4];
  const float* Wih1 = (const float*)d_in[5];
  const float* Whh1 = (const float*)d_in[6];
  const float* bih1 = (const float*)d_in[7];
  const float* bhh1 = (const float*)d_in[8];
  const float* Wlin = (const float*)d_in[9];
  const float* blin = (const float*)d_in[10];

  // ---- ws layout (~41.3 MiB; R1 proved ~43 MiB fits) ----
  uint8_t* p = (uint8_t*)d_ws;
  unsigned short* Wcf = (unsigned short*)p; p += (size_t)2 * 2048 * 1024 * 2;  // 8 MiB
  float* bias         = (float*)p;          p += (size_t)2 * 2048 * 4;         // 16 KiB
  unsigned short* h0x = (unsigned short*)p; p += (size_t)TS * SLAB * 2;        // 32 MiB
  unsigned short* h1r = (unsigned short*)p; p += (size_t)4 * SLAB * 2;         // 512 KiB
  float* Cst          = (float*)p;          p += (size_t)2 * SLAB * 4;         // 512 KiB
  float* H1f          = (float*)p;          p += (size_t)SLAB * 4;             // 256 KiB

  // deterministic init: cell state zero at sequence start (every call)
  hipMemsetAsync(Cst, 0, (size_t)2 * SLAB * 4, stream);

  prep_wcf<<<16384, 256, 0, stream>>>(Wih0, Whh0, Wih1, Whh1, Wcf);
  prep_bias<<<8, 256, 0, stream>>>(bih0, bhh0, bias);
  prep_bias<<<8, 256, 0, stream>>>(bih1, bhh1, bias + 2048);

  // 258 pipeline steps: L0 computes t=s (s<256), L1 computes t=s-2 (s>=2).
  for (int s = 0; s < TS + 2; ++s)
    lstm_step<<<256, 512, 0, stream>>>(text, Wcf, bias, h0x, h1r, Cst, H1f, s);

  final_linear<<<NB, 64, 0, stream>>>(H1f, Wlin, blin, (float*)d_out);
}

// Round 16
// 3497.443 us; speedup vs baseline: 1.2894x; 1.2894x over previous
//
#include <hip/hip_runtime.h>
#include <stdint.h>

// ---- problem constants ----
constexpr int HD   = 512;
constexpr int TS   = 256;
constexpr int NB   = 64;
constexpr int MBR  = 128;
constexpr int SLAB = MBR * HD;   // 65536 elements per h-slab
constexpr int NG   = 8;          // row groups (16 rows each)
constexpr int NS   = 16;         // unit slices (32 units each)

typedef __attribute__((ext_vector_type(8))) short bf16x8;
typedef __attribute__((ext_vector_type(4))) float f32x4;

__device__ __forceinline__ unsigned short f2bf(float f){
  union { float f; unsigned u; } v; v.f = f;
  unsigned r = v.u + 0x7fffu + ((v.u >> 16) & 1u);
  return (unsigned short)(r >> 16);
}
__device__ __forceinline__ float fsig(float x){ return 1.f / (1.f + __expf(-x)); }
__device__ __forceinline__ float ftanh(float x){ return 1.f - 2.f / (__expf(2.f * x) + 1.f); }
__device__ __forceinline__ void vdrain(){ asm volatile("s_waitcnt vmcnt(0)" ::: "memory"); }

// device-scope (memory-side, placement-independent) flag ops — R12-proven
__device__ __forceinline__ int ld_flag_sc1(const int* p){
  int v;
  asm volatile("global_load_dword %0, %1, off sc0 sc1\n\ts_waitcnt vmcnt(0)"
               : "=v"(v) : "v"(p) : "memory");
  return v;
}
__device__ __forceinline__ void st_sc1_b32(void* p, int v){
  asm volatile("global_store_dword %0, %1, off sc0 sc1" :: "v"(p), "v"(v) : "memory");
}

// 16 x 16B sc1 loads (one A-row K-half, 256B/lane). R12-proven pattern.
__device__ __forceinline__ void ld16_sc1(const void* p, f32x4* r){
  asm volatile(
    "global_load_dwordx4 %0,  %16, off sc0 sc1\n\t"
    "global_load_dwordx4 %1,  %16, off offset:64 sc0 sc1\n\t"
    "global_load_dwordx4 %2,  %16, off offset:128 sc0 sc1\n\t"
    "global_load_dwordx4 %3,  %16, off offset:192 sc0 sc1\n\t"
    "global_load_dwordx4 %4,  %16, off offset:256 sc0 sc1\n\t"
    "global_load_dwordx4 %5,  %16, off offset:320 sc0 sc1\n\t"
    "global_load_dwordx4 %6,  %16, off offset:384 sc0 sc1\n\t"
    "global_load_dwordx4 %7,  %16, off offset:448 sc0 sc1\n\t"
    "global_load_dwordx4 %8,  %16, off offset:512 sc0 sc1\n\t"
    "global_load_dwordx4 %9,  %16, off offset:576 sc0 sc1\n\t"
    "global_load_dwordx4 %10, %16, off offset:640 sc0 sc1\n\t"
    "global_load_dwordx4 %11, %16, off offset:704 sc0 sc1\n\t"
    "global_load_dwordx4 %12, %16, off offset:768 sc0 sc1\n\t"
    "global_load_dwordx4 %13, %16, off offset:832 sc0 sc1\n\t"
    "global_load_dwordx4 %14, %16, off offset:896 sc0 sc1\n\t"
    "global_load_dwordx4 %15, %16, off offset:960 sc0 sc1\n\t"
    "s_waitcnt vmcnt(0)"
    : "=&v"(r[0]), "=&v"(r[1]), "=&v"(r[2]), "=&v"(r[3]),
      "=&v"(r[4]), "=&v"(r[5]), "=&v"(r[6]), "=&v"(r[7]),
      "=&v"(r[8]), "=&v"(r[9]), "=&v"(r[10]), "=&v"(r[11]),
      "=&v"(r[12]), "=&v"(r[13]), "=&v"(r[14]), "=&v"(r[15])
    : "v"(p) : "memory");
}
__device__ __forceinline__ bf16x8 pack8(float4 a, float4 b){
  bf16x8 w;
  w[0]=(short)f2bf(a.x); w[1]=(short)f2bf(a.y); w[2]=(short)f2bf(a.z); w[3]=(short)f2bf(a.w);
  w[4]=(short)f2bf(b.x); w[5]=(short)f2bf(b.y); w[6]=(short)f2bf(b.z); w[7]=(short)f2bf(b.w);
  return w;
}

// Persistent pipelined 2-layer LSTM — placement-independent, 16-wide rendezvous.
// 256 WGs x 512 thr, 1 WG/CU.
// Role from blockIdx.x ONLY: layer = wg>>7; grp = (wg>>4)&7 (16 batch rows);
// slice = wg&15 (32 units). 16 independent 32-WG pipelines (one per grp).
// Per WG: 16 rows x 32 units x 4 gates = 128 gate-cols. Wave wv = col-frag
// (16 cols); all 8 waves share the same 16 A-rows.
// Weights: W_ih slice (128 KB) in LDS; W_hh slice in 64 VGPRs/lane (bPost).
// Sync (R12-proven protocol): sc1 packed h stores -> vmcnt -> barrier -> sc1
// flag; consumers poll 16 flags via sc1 loads + s_sleep, liveness-capped.
// h0x full-depth [256]: L0 free-runs; L1's input half is computed BEFORE the
// peer poll (hides peer-straggler tail). No circular waits.
__global__ __launch_bounds__(512, 1)
void lstm_persist(const float* __restrict__ text,
                  const float* __restrict__ Wih0, const float* __restrict__ Whh0,
                  const float* __restrict__ bih0, const float* __restrict__ bhh0,
                  const float* __restrict__ Wih1, const float* __restrict__ Whh1,
                  const float* __restrict__ bih1, const float* __restrict__ bhh1,
                  unsigned short* __restrict__ h0x,   // [256][128][512] write-once
                  unsigned short* __restrict__ h1r,   // [4][128][512] ring
                  float* __restrict__ H1f,            // [128][512] final h1 fp32
                  int* __restrict__ F)                // [2][8][256][16] flags
{
  extern __shared__ unsigned short Blds[];   // W_ih: 128 cols x 512 k, swizzled, 128 KB
  __shared__ int s_abort;

  const int wg    = blockIdx.x;
  const int layer = wg >> 7;
  const int grp   = (wg >> 4) & 7;
  const int slice = wg & 15;
  const int m0    = grp * 16;
  const int u0    = slice * 32;
  const int tid   = threadIdx.x;
  const int wv    = tid >> 6;     // col-frag index 0..7
  const int l     = tid & 63;
  const int lj    = l & 15;
  const int lk    = l >> 4;

  if (tid == 0) s_abort = 0;

  int* F0g = F + ((0 * NG + grp) * TS) * NS;   // layer-0 flags, this grp
  int* F1g = F + ((1 * NG + grp) * TS) * NS;   // layer-1 flags, this grp

  const float* Wihl = layer ? Wih1 : Wih0;
  const float* Whhl = layer ? Whh1 : Whh0;

  // ---- one-time: W_ih slice -> LDS (f32 -> bf16, swizzled) ----
  // col c (0..127): unit = u0 + (c>>2), gate = c&3; granule kg (0..63) = 8 elems.
  for (int it = tid; it < 128 * 64; it += 512){
    int c = it >> 6, kg = it & 63;
    int unit = u0 + (c >> 2);
    int gate = c & 3;
    const float* s = Wihl + (size_t)(gate * HD + unit) * HD + kg * 8;
    *(bf16x8*)((char*)Blds + c * 1024 + ((kg ^ (c & 7)) << 4)) =
        pack8(((const float4*)s)[0], ((const float4*)s)[1]);
  }

  // ---- one-time: W_hh slice -> registers (64 VGPR/lane) ----
  // lane's col j = wv*16 + lj -> unit = u0 + (j>>2), gate = j&3.
  const int j      = wv * 16 + lj;
  const int myunit = u0 + (j >> 2);
  const int mygate = j & 3;
  bf16x8 bPost[16];
  {
    const float* s0 = Whhl + (size_t)(mygate * HD + myunit) * HD + lk * 8;
    #pragma unroll
    for (int kk = 0; kk < 16; ++kk){
      const float* s = s0 + kk * 32;
      bPost[kk] = pack8(((const float4*)s)[0], ((const float4*)s)[1]);
    }
  }
  const float bgv = (layer ? bih1 : bih0)[mygate * HD + myunit]
                  + (layer ? bhh1 : bhh0)[mygate * HD + myunit];
  const int aoff  = (m0 + lj) * HD + lk * 8;    // A element offset (row, k)
  const int cboff = j * 1024;                   // W_ih col byte base in LDS
  const int swz   = lj & 7;

  float cst[4] = {0.f, 0.f, 0.f, 0.f};
  __syncthreads();   // LDS staged, s_abort visible

  auto ldsB = [&](int kg)->bf16x8 {
    return *(const bf16x8*)((const char*)Blds + cboff + ((kg ^ swz) << 4));
  };
  // wave-0 poll of 16 flags (all lanes mirror l&15). sc1. Liveness cap.
  auto pollwait = [&](const int* base){
    if (*(volatile int*)&s_abort) return;
    const int* fp = base + (l & 15);
    int it = 0;
    for (;;){
      int v = ld_flag_sc1(fp);
      if (__all(v != 0)) break;
      if (++it > 2000000){ s_abort = 1; break; }
      __builtin_amdgcn_s_sleep(1);
    }
  };
  // recurrent half: A from raw[] (already loaded), B from registers (bPost)
  auto postHalf = [&](const f32x4* raw, f32x4& acc){
    #pragma unroll
    for (int kk = 0; kk < 16; ++kk)
      acc = __builtin_amdgcn_mfma_f32_16x16x32_bf16(
              __builtin_bit_cast(bf16x8, raw[kk]), bPost[kk], acc, 0, 0, 0);
  };
  // cell update; packed sc1 h store (dword = 2 units); optional fp32 final write
  auto cellstore = [&](const f32x4& aP, const f32x4& aQ,
                       unsigned short* __restrict__ hslab, bool wrF){
    #pragma unroll
    for (int r = 0; r < 4; ++r){
      float v  = aP[r] + aQ[r] + bgv;
      float v1 = __shfl_xor(v, 1);
      float v2 = __shfl_xor(v, 2);
      float v3 = __shfl_xor(v, 3);
      auto pick = [&](int m)->float {
        return m == 0 ? v : (m == 1 ? v1 : (m == 2 ? v2 : v3));
      };
      float gi = pick(mygate);
      float gf = pick(mygate ^ 1);
      float gg = pick(mygate ^ 2);
      float go = pick(mygate ^ 3);
      float i_ = fsig(gi);
      float f_ = fsig(gf);
      float g_ = ftanh(gg);
      float o_ = fsig(go);
      float c  = f_ * cst[r] + i_ * g_;
      cst[r] = c;
      float h  = o_ * ftanh(c);
      int row  = m0 + lk * 4 + r;
      int hb   = (int)f2bf(h);
      int pb   = __shfl_xor(hb, 4);          // partner unit (myunit+1)
      if ((j & 7) == 0)                      // j in {0,8,...}: even-unit, gate 0
        st_sc1_b32((char*)hslab + ((size_t)row * HD + myunit) * 2,
                   (hb & 0xffff) | (pb << 16));
      if (wrF && mygate == 0)
        H1f[(size_t)row * HD + myunit] = h;
    }
  };
  // L0 input projection: text f32 direct (plain cached), cvt in-flight, W_ih LDS
  auto preX = [&](int t, f32x4& acc){
    int arow = m0 + lj;
    int b    = arow & 63;
    int ts2  = (arow < 64) ? t : (TS - 1 - t);
    const float* src = text + ((size_t)b * TS + ts2) * HD + lk * 8;
    acc = (f32x4){0.f, 0.f, 0.f, 0.f};
    #pragma unroll
    for (int kk = 0; kk < 16; ++kk){
      const float* s = src + kk * 32;
      bf16x8 a = pack8(((const float4*)s)[0], ((const float4*)s)[1]);
      acc = __builtin_amdgcn_mfma_f32_16x16x32_bf16(a, ldsB(kk * 4 + lk), acc, 0, 0, 0);
    }
  };

  if (layer == 0){
    // ================= layer 0: free-running (no backpressure ever) ==========
    f32x4 accPre;
    preX(0, accPre);
    for (int t = 0; t < TS; ++t){
      f32x4 accPost = {0.f, 0.f, 0.f, 0.f};
      if (t > 0){
        if (wv == 0) pollwait(F0g + (t - 1) * NS);
        __syncthreads();
        f32x4 raw[16];
        ld16_sc1(h0x + (size_t)(t - 1) * SLAB + aoff, raw);
        postHalf(raw, accPost);
      }
      cellstore(accPre, accPost, h0x + (size_t)t * SLAB, false);
      vdrain();                 // sc1 stores acked at coherence point
      __syncthreads();
      if (tid == 0) st_sc1_b32(F0g + t * NS + slice, 1);
      if (t + 1 < TS) preX(t + 1, accPre);   // off critical path
    }
  } else {
    // ================= layer 1: chases L0 ====================================
    for (int t = 0; t < TS; ++t){
      // -- input half first: F0[t] poll is near-instant (L0 runs far ahead) --
      if (wv == 0) pollwait(F0g + t * NS);
      __syncthreads();
      f32x4 accPre = {0.f, 0.f, 0.f, 0.f};
      {
        f32x4 rawI[16];
        ld16_sc1(h0x + (size_t)t * SLAB + aoff, rawI);
        #pragma unroll
        for (int kk = 0; kk < 16; ++kk)
          accPre = __builtin_amdgcn_mfma_f32_16x16x32_bf16(
                     __builtin_bit_cast(bf16x8, rawI[kk]), ldsB(kk * 4 + lk),
                     accPre, 0, 0, 0);
      }
      // -- recurrent half: gated on peers' t-1 (the pacing dependency) --
      f32x4 accPost = {0.f, 0.f, 0.f, 0.f};
      if (t > 0){
        if (wv == 0) pollwait(F1g + (t - 1) * NS);
        __syncthreads();
        f32x4 rawR[16];
        ld16_sc1(h1r + (size_t)((t - 1) & 3) * SLAB + aoff, rawR);
        postHalf(rawR, accPost);
      }
      cellstore(accPre, accPost, h1r + (size_t)(t & 3) * SLAB, t == TS - 1);
      vdrain();
      __syncthreads();
      if (tid == 0) st_sc1_b32(F1g + t * NS + slice, 1);
    }
  }
}

// out[b] = dot(h1_fwd[b], Wlin[0:512]) + dot(h1_rev[b], Wlin[512:1024]) + blin
__global__ void final_linear(const float* __restrict__ H1f, const float* __restrict__ Wlin,
                             const float* __restrict__ blin, float* __restrict__ out){
  int b = blockIdx.x, l = threadIdx.x;
  float s = 0.f;
  for (int jj = l; jj < HD; jj += 64) s += H1f[(size_t)b * HD + jj]        * Wlin[jj];
  for (int jj = l; jj < HD; jj += 64) s += H1f[(size_t)(NB + b) * HD + jj] * Wlin[HD + jj];
  #pragma unroll
  for (int off = 32; off; off >>= 1) s += __shfl_down(s, off);
  if (l == 0) out[b] = s + blin[0];
}

extern "C" void kernel_launch(void* const* d_in, const int* in_sizes, int n_in,
                              void* d_out, int out_size, void* d_ws, size_t ws_size,
                              hipStream_t stream)
{
  const float* text = (const float*)d_in[0];
  const float* Wih0 = (const float*)d_in[1];
  const float* Whh0 = (const float*)d_in[2];
  const float* bih0 = (const float*)d_in[3];
  const float* bhh0 = (const float*)d_in[4];
  const float* Wih1 = (const float*)d_in[5];
  const float* Whh1 = (const float*)d_in[6];
  const float* bih1 = (const float*)d_in[7];
  const float* bhh1 = (const float*)d_in[8];
  const float* Wlin = (const float*)d_in[9];
  const float* blin = (const float*)d_in[10];

  // ---- ws layout (~33 MiB) ----
  uint8_t* p = (uint8_t*)d_ws;
  unsigned short* h0x = (unsigned short*)p; p += (size_t)TS * SLAB * 2;        // 32 MiB
  unsigned short* h1r = (unsigned short*)p; p += (size_t)4 * SLAB * 2;         // 512 KiB
  float* H1f          = (float*)p;          p += (size_t)SLAB * 4;             // 256 KiB
  int* F              = (int*)p;            p += (size_t)2 * NG * TS * NS * 4; // 256 KiB

  // deterministic init: flags zero at kernel start
  hipMemsetAsync(F, 0, (size_t)2 * NG * TS * NS * 4, stream);

  hipFuncSetAttribute((const void*)lstm_persist,
                      hipFuncAttributeMaxDynamicSharedMemorySize, 131072);

  const float* A0 = text;
  const float *A1 = Wih0, *A2 = Whh0, *A3 = bih0, *A4 = bhh0;
  const float *A5 = Wih1, *A6 = Whh1, *A7 = bih1, *A8 = bhh1;
  unsigned short* B0 = h0x; unsigned short* B1 = h1r;
  float* B2 = H1f; int* B3 = F;
  void* args[] = {(void*)&A0,
                  (void*)&A1, (void*)&A2, (void*)&A3, (void*)&A4,
                  (void*)&A5, (void*)&A6, (void*)&A7, (void*)&A8,
                  (void*)&B0, (void*)&B1, (void*)&B2, (void*)&B3};
  hipLaunchCooperativeKernel((void*)lstm_persist, dim3(256), dim3(512),
                             args, 131072, stream);

  final_linear<<<NB, 64, 0, stream>>>(H1f, Wlin, blin, (float*)d_out);
}

// Round 17
// 3493.153 us; speedup vs baseline: 1.2910x; 1.0012x over previous
//
#include <hip/hip_runtime.h>
#include <stdint.h>

// ---- problem constants ----
constexpr int HD   = 512;
constexpr int TS   = 256;
constexpr int NB   = 64;
constexpr int MBR  = 128;
constexpr int SLAB = MBR * HD;   // 65536 elements per h-slab
constexpr int NG   = 8;          // row groups (16 rows each)
constexpr int NS   = 16;         // unit slices (32 units each)

typedef __attribute__((ext_vector_type(8))) short bf16x8;
typedef __attribute__((ext_vector_type(4))) float f32x4;

__device__ __forceinline__ unsigned short f2bf(float f){
  union { float f; unsigned u; } v; v.f = f;
  unsigned r = v.u + 0x7fffu + ((v.u >> 16) & 1u);
  return (unsigned short)(r >> 16);
}
__device__ __forceinline__ float fsig(float x){ return 1.f / (1.f + __expf(-x)); }
__device__ __forceinline__ float ftanh(float x){ return 1.f - 2.f / (__expf(2.f * x) + 1.f); }
__device__ __forceinline__ void vdrain(){ asm volatile("s_waitcnt vmcnt(0)" ::: "memory"); }

// device-scope (memory-side, placement-independent) flag ops — R12-proven
__device__ __forceinline__ int ld_flag_sc1(const int* p){
  int v;
  asm volatile("global_load_dword %0, %1, off sc0 sc1\n\ts_waitcnt vmcnt(0)"
               : "=v"(v) : "v"(p) : "memory");
  return v;
}
__device__ __forceinline__ void st_sc1_b32(void* p, int v){
  asm volatile("global_store_dword %0, %1, off sc0 sc1" :: "v"(p), "v"(v) : "memory");
}

// 16 x 16B sc1 loads (one A-row K-half, 256B/lane). R12-proven pattern.
__device__ __forceinline__ void ld16_sc1(const void* p, f32x4* r){
  asm volatile(
    "global_load_dwordx4 %0,  %16, off sc0 sc1\n\t"
    "global_load_dwordx4 %1,  %16, off offset:64 sc0 sc1\n\t"
    "global_load_dwordx4 %2,  %16, off offset:128 sc0 sc1\n\t"
    "global_load_dwordx4 %3,  %16, off offset:192 sc0 sc1\n\t"
    "global_load_dwordx4 %4,  %16, off offset:256 sc0 sc1\n\t"
    "global_load_dwordx4 %5,  %16, off offset:320 sc0 sc1\n\t"
    "global_load_dwordx4 %6,  %16, off offset:384 sc0 sc1\n\t"
    "global_load_dwordx4 %7,  %16, off offset:448 sc0 sc1\n\t"
    "global_load_dwordx4 %8,  %16, off offset:512 sc0 sc1\n\t"
    "global_load_dwordx4 %9,  %16, off offset:576 sc0 sc1\n\t"
    "global_load_dwordx4 %10, %16, off offset:640 sc0 sc1\n\t"
    "global_load_dwordx4 %11, %16, off offset:704 sc0 sc1\n\t"
    "global_load_dwordx4 %12, %16, off offset:768 sc0 sc1\n\t"
    "global_load_dwordx4 %13, %16, off offset:832 sc0 sc1\n\t"
    "global_load_dwordx4 %14, %16, off offset:896 sc0 sc1\n\t"
    "global_load_dwordx4 %15, %16, off offset:960 sc0 sc1\n\t"
    "s_waitcnt vmcnt(0)"
    : "=&v"(r[0]), "=&v"(r[1]), "=&v"(r[2]), "=&v"(r[3]),
      "=&v"(r[4]), "=&v"(r[5]), "=&v"(r[6]), "=&v"(r[7]),
      "=&v"(r[8]), "=&v"(r[9]), "=&v"(r[10]), "=&v"(r[11]),
      "=&v"(r[12]), "=&v"(r[13]), "=&v"(r[14]), "=&v"(r[15])
    : "v"(p) : "memory");
}
__device__ __forceinline__ bf16x8 pack8(float4 a, float4 b){
  bf16x8 w;
  w[0]=(short)f2bf(a.x); w[1]=(short)f2bf(a.y); w[2]=(short)f2bf(a.z); w[3]=(short)f2bf(a.w);
  w[4]=(short)f2bf(b.x); w[5]=(short)f2bf(b.y); w[6]=(short)f2bf(b.z); w[7]=(short)f2bf(b.w);
  return w;
}

// Persistent pipelined 2-layer LSTM — placement-independent, 16-wide rendezvous.
// IDENTICAL to R16 except pollwait: busy-spin (no s_sleep) for the first 4096
// iterations, then s_sleep(1) backoff; same 2M liveness cap. Single-variable
// A/B vs R16's 3497 us to isolate poll-detect latency + DVFS downclock.
__global__ __launch_bounds__(512, 1)
void lstm_persist(const float* __restrict__ text,
                  const float* __restrict__ Wih0, const float* __restrict__ Whh0,
                  const float* __restrict__ bih0, const float* __restrict__ bhh0,
                  const float* __restrict__ Wih1, const float* __restrict__ Whh1,
                  const float* __restrict__ bih1, const float* __restrict__ bhh1,
                  unsigned short* __restrict__ h0x,   // [256][128][512] write-once
                  unsigned short* __restrict__ h1r,   // [4][128][512] ring
                  float* __restrict__ H1f,            // [128][512] final h1 fp32
                  int* __restrict__ F)                // [2][8][256][16] flags
{
  extern __shared__ unsigned short Blds[];   // W_ih: 128 cols x 512 k, swizzled, 128 KB
  __shared__ int s_abort;

  const int wg    = blockIdx.x;
  const int layer = wg >> 7;
  const int grp   = (wg >> 4) & 7;
  const int slice = wg & 15;
  const int m0    = grp * 16;
  const int u0    = slice * 32;
  const int tid   = threadIdx.x;
  const int wv    = tid >> 6;     // col-frag index 0..7
  const int l     = tid & 63;
  const int lj    = l & 15;
  const int lk    = l >> 4;

  if (tid == 0) s_abort = 0;

  int* F0g = F + ((0 * NG + grp) * TS) * NS;   // layer-0 flags, this grp
  int* F1g = F + ((1 * NG + grp) * TS) * NS;   // layer-1 flags, this grp

  const float* Wihl = layer ? Wih1 : Wih0;
  const float* Whhl = layer ? Whh1 : Whh0;

  // ---- one-time: W_ih slice -> LDS (f32 -> bf16, swizzled) ----
  for (int it = tid; it < 128 * 64; it += 512){
    int c = it >> 6, kg = it & 63;
    int unit = u0 + (c >> 2);
    int gate = c & 3;
    const float* s = Wihl + (size_t)(gate * HD + unit) * HD + kg * 8;
    *(bf16x8*)((char*)Blds + c * 1024 + ((kg ^ (c & 7)) << 4)) =
        pack8(((const float4*)s)[0], ((const float4*)s)[1]);
  }

  // ---- one-time: W_hh slice -> registers (64 VGPR/lane) ----
  const int j      = wv * 16 + lj;
  const int myunit = u0 + (j >> 2);
  const int mygate = j & 3;
  bf16x8 bPost[16];
  {
    const float* s0 = Whhl + (size_t)(mygate * HD + myunit) * HD + lk * 8;
    #pragma unroll
    for (int kk = 0; kk < 16; ++kk){
      const float* s = s0 + kk * 32;
      bPost[kk] = pack8(((const float4*)s)[0], ((const float4*)s)[1]);
    }
  }
  const float bgv = (layer ? bih1 : bih0)[mygate * HD + myunit]
                  + (layer ? bhh1 : bhh0)[mygate * HD + myunit];
  const int aoff  = (m0 + lj) * HD + lk * 8;    // A element offset (row, k)
  const int cboff = j * 1024;                   // W_ih col byte base in LDS
  const int swz   = lj & 7;

  float cst[4] = {0.f, 0.f, 0.f, 0.f};
  __syncthreads();   // LDS staged, s_abort visible

  auto ldsB = [&](int kg)->bf16x8 {
    return *(const bf16x8*)((const char*)Blds + cboff + ((kg ^ swz) << 4));
  };
  // wave-0 poll of 16 flags. THE round-17 delta: hot busy-spin first (no
  // sleep; covers all steady-state waits), sleep backoff only after 4096
  // iters, liveness cap at 2M (deadlock-free protocol -> cap never fires
  // unless something is broken; converts a stall into a fast wrong answer).
  auto pollwait = [&](const int* base){
    if (*(volatile int*)&s_abort) return;
    const int* fp = base + (l & 15);
    int it = 0;
    for (;;){
      int v = ld_flag_sc1(fp);
      if (__all(v != 0)) break;
      ++it;
      if (it > 4096){
        if (it > 2000000){ s_abort = 1; break; }
        __builtin_amdgcn_s_sleep(1);
      }
    }
  };
  // recurrent half: A from raw[] (already loaded), B from registers (bPost)
  auto postHalf = [&](const f32x4* raw, f32x4& acc){
    #pragma unroll
    for (int kk = 0; kk < 16; ++kk)
      acc = __builtin_amdgcn_mfma_f32_16x16x32_bf16(
              __builtin_bit_cast(bf16x8, raw[kk]), bPost[kk], acc, 0, 0, 0);
  };
  // cell update; packed sc1 h store (dword = 2 units); optional fp32 final write
  auto cellstore = [&](const f32x4& aP, const f32x4& aQ,
                       unsigned short* __restrict__ hslab, bool wrF){
    #pragma unroll
    for (int r = 0; r < 4; ++r){
      float v  = aP[r] + aQ[r] + bgv;
      float v1 = __shfl_xor(v, 1);
      float v2 = __shfl_xor(v, 2);
      float v3 = __shfl_xor(v, 3);
      auto pick = [&](int m)->float {
        return m == 0 ? v : (m == 1 ? v1 : (m == 2 ? v2 : v3));
      };
      float gi = pick(mygate);
      float gf = pick(mygate ^ 1);
      float gg = pick(mygate ^ 2);
      float go = pick(mygate ^ 3);
      float i_ = fsig(gi);
      float f_ = fsig(gf);
      float g_ = ftanh(gg);
      float o_ = fsig(go);
      float c  = f_ * cst[r] + i_ * g_;
      cst[r] = c;
      float h  = o_ * ftanh(c);
      int row  = m0 + lk * 4 + r;
      int hb   = (int)f2bf(h);
      int pb   = __shfl_xor(hb, 4);          // partner unit (myunit+1)
      if ((j & 7) == 0)                      // even-unit, gate 0 lanes
        st_sc1_b32((char*)hslab + ((size_t)row * HD + myunit) * 2,
                   (hb & 0xffff) | (pb << 16));
      if (wrF && mygate == 0)
        H1f[(size_t)row * HD + myunit] = h;
    }
  };
  // L0 input projection: text f32 direct (plain cached), cvt in-flight, W_ih LDS
  auto preX = [&](int t, f32x4& acc){
    int arow = m0 + lj;
    int b    = arow & 63;
    int ts2  = (arow < 64) ? t : (TS - 1 - t);
    const float* src = text + ((size_t)b * TS + ts2) * HD + lk * 8;
    acc = (f32x4){0.f, 0.f, 0.f, 0.f};
    #pragma unroll
    for (int kk = 0; kk < 16; ++kk){
      const float* s = src + kk * 32;
      bf16x8 a = pack8(((const float4*)s)[0], ((const float4*)s)[1]);
      acc = __builtin_amdgcn_mfma_f32_16x16x32_bf16(a, ldsB(kk * 4 + lk), acc, 0, 0, 0);
    }
  };

  if (layer == 0){
    // ================= layer 0: free-running (no backpressure ever) ==========
    f32x4 accPre;
    preX(0, accPre);
    for (int t = 0; t < TS; ++t){
      f32x4 accPost = {0.f, 0.f, 0.f, 0.f};
      if (t > 0){
        if (wv == 0) pollwait(F0g + (t - 1) * NS);
        __syncthreads();
        f32x4 raw[16];
        ld16_sc1(h0x + (size_t)(t - 1) * SLAB + aoff, raw);
        postHalf(raw, accPost);
      }
      cellstore(accPre, accPost, h0x + (size_t)t * SLAB, false);
      vdrain();                 // sc1 stores acked at coherence point
      __syncthreads();
      if (tid == 0) st_sc1_b32(F0g + t * NS + slice, 1);
      if (t + 1 < TS) preX(t + 1, accPre);   // off critical path
    }
  } else {
    // ================= layer 1: chases L0 ====================================
    for (int t = 0; t < TS; ++t){
      // -- input half first: F0[t] poll is near-instant (L0 runs ahead) --
      if (wv == 0) pollwait(F0g + t * NS);
      __syncthreads();
      f32x4 accPre = {0.f, 0.f, 0.f, 0.f};
      {
        f32x4 rawI[16];
        ld16_sc1(h0x + (size_t)t * SLAB + aoff, rawI);
        #pragma unroll
        for (int kk = 0; kk < 16; ++kk)
          accPre = __builtin_amdgcn_mfma_f32_16x16x32_bf16(
                     __builtin_bit_cast(bf16x8, rawI[kk]), ldsB(kk * 4 + lk),
                     accPre, 0, 0, 0);
      }
      // -- recurrent half: gated on peers' t-1 (the pacing dependency) --
      f32x4 accPost = {0.f, 0.f, 0.f, 0.f};
      if (t > 0){
        if (wv == 0) pollwait(F1g + (t - 1) * NS);
        __syncthreads();
        f32x4 rawR[16];
        ld16_sc1(h1r + (size_t)((t - 1) & 3) * SLAB + aoff, rawR);
        postHalf(rawR, accPost);
      }
      cellstore(accPre, accPost, h1r + (size_t)(t & 3) * SLAB, t == TS - 1);
      vdrain();
      __syncthreads();
      if (tid == 0) st_sc1_b32(F1g + t * NS + slice, 1);
    }
  }
}

// out[b] = dot(h1_fwd[b], Wlin[0:512]) + dot(h1_rev[b], Wlin[512:1024]) + blin
__global__ void final_linear(const float* __restrict__ H1f, const float* __restrict__ Wlin,
                             const float* __restrict__ blin, float* __restrict__ out){
  int b = blockIdx.x, l = threadIdx.x;
  float s = 0.f;
  for (int jj = l; jj < HD; jj += 64) s += H1f[(size_t)b * HD + jj]        * Wlin[jj];
  for (int jj = l; jj < HD; jj += 64) s += H1f[(size_t)(NB + b) * HD + jj] * Wlin[HD + jj];
  #pragma unroll
  for (int off = 32; off; off >>= 1) s += __shfl_down(s, off);
  if (l == 0) out[b] = s + blin[0];
}

extern "C" void kernel_launch(void* const* d_in, const int* in_sizes, int n_in,
                              void* d_out, int out_size, void* d_ws, size_t ws_size,
                              hipStream_t stream)
{
  const float* text = (const float*)d_in[0];
  const float* Wih0 = (const float*)d_in[1];
  const float* Whh0 = (const float*)d_in[2];
  const float* bih0 = (const float*)d_in[3];
  const float* bhh0 = (const float*)d_in[4];
  const float* Wih1 = (const float*)d_in[5];
  const float* Whh1 = (const float*)d_in[6];
  const float* bih1 = (const float*)d_in[7];
  const float* bhh1 = (const float*)d_in[8];
  const float* Wlin = (const float*)d_in[9];
  const float* blin = (const float*)d_in[10];

  // ---- ws layout (~33 MiB) ----
  uint8_t* p = (uint8_t*)d_ws;
  unsigned short* h0x = (unsigned short*)p; p += (size_t)TS * SLAB * 2;        // 32 MiB
  unsigned short* h1r = (unsigned short*)p; p += (size_t)4 * SLAB * 2;         // 512 KiB
  float* H1f          = (float*)p;          p += (size_t)SLAB * 4;             // 256 KiB
  int* F              = (int*)p;            p += (size_t)2 * NG * TS * NS * 4; // 256 KiB

  // deterministic init: flags zero at kernel start
  hipMemsetAsync(F, 0, (size_t)2 * NG * TS * NS * 4, stream);

  hipFuncSetAttribute((const void*)lstm_persist,
                      hipFuncAttributeMaxDynamicSharedMemorySize, 131072);

  const float* A0 = text;
  const float *A1 = Wih0, *A2 = Whh0, *A3 = bih0, *A4 = bhh0;
  const float *A5 = Wih1, *A6 = Whh1, *A7 = bih1, *A8 = bhh1;
  unsigned short* B0 = h0x; unsigned short* B1 = h1r;
  float* B2 = H1f; int* B3 = F;
  void* args[] = {(void*)&A0,
                  (void*)&A1, (void*)&A2, (void*)&A3, (void*)&A4,
                  (void*)&A5, (void*)&A6, (void*)&A7, (void*)&A8,
                  (void*)&B0, (void*)&B1, (void*)&B2, (void*)&B3};
  hipLaunchCooperativeKernel((void*)lstm_persist, dim3(256), dim3(512),
                             args, 131072, stream);

  final_linear<<<NB, 64, 0, stream>>>(H1f, Wlin, blin, (float*)d_out);
}